// Round 2
// baseline (239.430 us; speedup 1.0000x reference)
//
#include <hip/hip_runtime.h>

#define N_NODES 100000
#define N_EDGES 1600000
#define IN_DIM 128
#define HID 64
#define OUT_DIM 64

typedef __attribute__((ext_vector_type(8))) short short8;
typedef __attribute__((ext_vector_type(4))) float f32x4;
union FragU { short8 v; unsigned u[4]; };

__device__ __forceinline__ unsigned bf16r(float f) {   // fp32 -> bf16 bits, RNE
    unsigned u = __float_as_uint(f);
    return (u + 0x7FFFu + ((u >> 16) & 1u)) >> 16;
}
__device__ __forceinline__ float blo(unsigned u) { return __uint_as_float(u << 16); }
__device__ __forceinline__ float bhi(unsigned u) { return __uint_as_float(u & 0xFFFF0000u); }

#define K1_BLOCKS 1563          // ceil(6250 tiles / 4 waves)
#define NB 391                  // coarse buckets: dst >> 8
#define CAP 4608                // per-bucket capacity (mean ~4092, +8 sigma)
#define P1_BLOCKS 782           // 2048 edges per block, 512 threads, 1 int4/thread

// ---------------- P1: coarse bucket scatter (separate kernel) ----------------
// 782 blocks x 512 thr -> ~24 waves/CU of TLP for the latency-bound scatter.
// Per-edge ranks via LDS atomics; ~258K conditional global returning atomics.
__global__ __launch_bounds__(512) void p1_bucket(const int* __restrict__ ei,
                                                 int* __restrict__ gcount,
                                                 unsigned* __restrict__ ibuf) {
    __shared__ int cnt[NB], base[NB];
    const int tid = threadIdx.x;
    const int i4 = blockIdx.x * 512 + tid;
    for (int i = tid; i < NB; i += 512) cnt[i] = 0;
    __syncthreads();
    int pk[4] = {0, 0, 0, 0};                 // dst | local_rank<<17
    const bool ok = (i4 < N_EDGES / 4);
    if (ok) {
        int4 dv = ((const int4*)(ei + N_EDGES))[i4];
        pk[0] = dv.x | (atomicAdd(&cnt[dv.x >> 8], 1) << 17);
        pk[1] = dv.y | (atomicAdd(&cnt[dv.y >> 8], 1) << 17);
        pk[2] = dv.z | (atomicAdd(&cnt[dv.z >> 8], 1) << 17);
        pk[3] = dv.w | (atomicAdd(&cnt[dv.w >> 8], 1) << 17);
    }
    __syncthreads();
    for (int b = tid; b < NB; b += 512) {     // one returning atomic per non-empty bucket
        int c = cnt[b];
        base[b] = c ? atomicAdd(&gcount[b], c) : 0;
    }
    __syncthreads();
    if (ok) {
        int4 sv = ((const int4*)ei)[i4];
        int srcs[4] = {sv.x, sv.y, sv.z, sv.w};
#pragma unroll
        for (int j = 0; j < 4; ++j) {
            unsigned p   = (unsigned)pk[j];
            unsigned dst = p & 0x1FFFFu;
            unsigned r   = p >> 17;
            unsigned bk  = dst >> 8;
            ibuf[bk * CAP + (unsigned)base[bk] + r] =
                (unsigned)srcs[j] | ((dst & 255u) << 20);
        }
    }
}

// ---------------- K1: h(bf16) = x @ W^T via MFMA; s,d exact fp32 -------------
__global__ __launch_bounds__(256) void k1_lin(const float* __restrict__ x,
                                              const float* __restrict__ W,
                                              const float* __restrict__ att,
                                              uint4* __restrict__ h4,
                                              float* __restrict__ s,
                                              float* __restrict__ d) {
    __shared__ float wsL[IN_DIM], wdL[IN_DIM];
    __shared__ float scratch[4 * 64 * 17];   // per-wave [col][row] stride 17
    const int tid = threadIdx.x;

    if (tid < IN_DIM) {
        float as = 0.f, ad = 0.f;
        for (int c = 0; c < HID; ++c) {
            float w = W[c * IN_DIM + tid];
            as += w * att[c];
            ad += w * att[HID + c];
        }
        wsL[tid] = as; wdL[tid] = ad;
    }
    __syncthreads();

    const int lane = tid & 63;
    const int wv = tid >> 6;
    const int l16 = lane & 15;
    const int quad = lane >> 4;
    const int tile = blockIdx.x * 4 + wv;

    FragU bfrag[4][4];
#pragma unroll
    for (int t = 0; t < 4; ++t) {
#pragma unroll
        for (int ks = 0; ks < 4; ++ks) {
            const float* wp = &W[(t * 16 + l16) * IN_DIM + ks * 32 + quad * 8];
            float4 wa = *(const float4*)wp;
            float4 wb = *(const float4*)(wp + 4);
            bfrag[t][ks].u[0] = bf16r(wa.x) | (bf16r(wa.y) << 16);
            bfrag[t][ks].u[1] = bf16r(wa.z) | (bf16r(wa.w) << 16);
            bfrag[t][ks].u[2] = bf16r(wb.x) | (bf16r(wb.y) << 16);
            bfrag[t][ks].u[3] = bf16r(wb.z) | (bf16r(wb.w) << 16);
        }
    }

    if (tile < N_NODES / 16) {
        const int rowbase = tile * 16;
        const float* xrow = &x[(size_t)(rowbase + l16) * IN_DIM];
        f32x4 acc[4] = {{0.f,0.f,0.f,0.f},{0.f,0.f,0.f,0.f},
                        {0.f,0.f,0.f,0.f},{0.f,0.f,0.f,0.f}};
        float ps = 0.f, pd = 0.f;
#pragma unroll
        for (int ks = 0; ks < 4; ++ks) {
            const int k0 = ks * 32 + quad * 8;
            float4 xa = *(const float4*)&xrow[k0];
            float4 xb = *(const float4*)&xrow[k0 + 4];
            ps += xa.x * wsL[k0]     + xa.y * wsL[k0 + 1]
                + xa.z * wsL[k0 + 2] + xa.w * wsL[k0 + 3]
                + xb.x * wsL[k0 + 4] + xb.y * wsL[k0 + 5]
                + xb.z * wsL[k0 + 6] + xb.w * wsL[k0 + 7];
            pd += xa.x * wdL[k0]     + xa.y * wdL[k0 + 1]
                + xa.z * wdL[k0 + 2] + xa.w * wdL[k0 + 3]
                + xb.x * wdL[k0 + 4] + xb.y * wdL[k0 + 5]
                + xb.z * wdL[k0 + 6] + xb.w * wdL[k0 + 7];
            FragU af;
            af.u[0] = bf16r(xa.x) | (bf16r(xa.y) << 16);
            af.u[1] = bf16r(xa.z) | (bf16r(xa.w) << 16);
            af.u[2] = bf16r(xb.x) | (bf16r(xb.y) << 16);
            af.u[3] = bf16r(xb.z) | (bf16r(xb.w) << 16);
#pragma unroll
            for (int t = 0; t < 4; ++t)
                acc[t] = __builtin_amdgcn_mfma_f32_16x16x32_bf16(
                    af.v, bfrag[t][ks].v, acc[t], 0, 0, 0);
        }
        ps += __shfl_xor(ps, 16, 64); ps += __shfl_xor(ps, 32, 64);
        pd += __shfl_xor(pd, 16, 64); pd += __shfl_xor(pd, 32, 64);
        if (quad == 0) { s[rowbase + l16] = ps; d[rowbase + l16] = pd; }
        float* sc = &scratch[wv * 64 * 17];
#pragma unroll
        for (int t = 0; t < 4; ++t)
#pragma unroll
            for (int r = 0; r < 4; ++r)
                sc[(l16 + 16 * t) * 17 + quad * 4 + r] = acc[t][r];
        // same-wave RAW through LDS: compiler inserts lgkmcnt wait
#pragma unroll
        for (int i = 0; i < 2; ++i) {
            int idx = i * 64 + lane;
            int nrow = idx >> 3, q = idx & 7;
            float v0 = sc[(q * 8 + 0) * 17 + nrow];
            float v1 = sc[(q * 8 + 1) * 17 + nrow];
            float v2 = sc[(q * 8 + 2) * 17 + nrow];
            float v3 = sc[(q * 8 + 3) * 17 + nrow];
            float v4 = sc[(q * 8 + 4) * 17 + nrow];
            float v5 = sc[(q * 8 + 5) * 17 + nrow];
            float v6 = sc[(q * 8 + 6) * 17 + nrow];
            float v7 = sc[(q * 8 + 7) * 17 + nrow];
            uint4 o;
            o.x = bf16r(v0) | (bf16r(v1) << 16);
            o.y = bf16r(v2) | (bf16r(v3) << 16);
            o.z = bf16r(v4) | (bf16r(v5) << 16);
            o.w = bf16r(v6) | (bf16r(v7) << 16);
            h4[(size_t)(rowbase + nrow) * 8 + q] = o;
        }
    }
}

// ---------------- Pass 2: per-bucket LDS counting sort + edge attention ------
// One block per coarse bucket (~4096 edges, 256 dsts). 1024 threads; shfl scan
// (2 barriers); physical LDS reorder so the final sorted write is coalesced.
__global__ __launch_bounds__(1024) void k_bucket2(const unsigned* __restrict__ ibuf,
                                                  const int* __restrict__ gcount,
                                                  const float* __restrict__ s,
                                                  const float* __restrict__ d,
                                                  int* __restrict__ row_start,
                                                  uint2* __restrict__ sorted) {
    __shared__ unsigned el[CAP];
    __shared__ unsigned el2[CAP];
    __shared__ unsigned short rk[CAP];
    __shared__ int cnt2[256], off2[256];
    __shared__ float dloc[256];
    __shared__ int wred[16];
    __shared__ int base_s, cnt_s;
    const int tid  = threadIdx.x;
    const int lane = tid & 63;
    const int wv   = tid >> 6;
    const int b    = blockIdx.x;

    // global base of this bucket = sum of gcount[0..b)
    int part = 0;
    for (int j = tid; j < b; j += 1024) part += gcount[j];
#pragma unroll
    for (int off = 32; off > 0; off >>= 1) part += __shfl_xor(part, off, 64);
    if (lane == 0) wred[wv] = part;
    if (tid < 256) {
        cnt2[tid] = 0;
        int dn = b * 256 + tid;
        dloc[tid] = (dn < N_NODES) ? d[dn] : 0.f;
    }
    __syncthreads();
    if (tid == 0) {
        int t = 0;
#pragma unroll
        for (int w = 0; w < 16; ++w) t += wred[w];
        base_s = t;
        cnt_s = gcount[b];
    }
    __syncthreads();
    const int base  = base_s;
    const int count = cnt_s;

    // phase A: stage edges in LDS, per-dst ranks via LDS atomics
    for (int k = tid; k < count; k += 1024) {
        unsigned v = ibuf[b * CAP + k];
        int dl = (int)(v >> 20);
        int r = atomicAdd(&cnt2[dl], 1);
        el[k] = v;
        rk[k] = (unsigned short)r;
    }
    __syncthreads();

    // phase B: exclusive scan of 256 counters via shfl (2 barriers)
    int v0 = 0, sc0 = 0;
    if (tid < 256) {
        v0 = cnt2[tid];
        sc0 = v0;
#pragma unroll
        for (int off = 1; off < 64; off <<= 1) {
            int t = __shfl_up(sc0, off, 64);
            if (lane >= off) sc0 += t;
        }
        if (lane == 63) wred[wv] = sc0;     // wv in 0..3 here
    }
    __syncthreads();
    if (tid < 256) {
        int wp = 0;
#pragma unroll
        for (int w = 0; w < 4; ++w) {
            int t = wred[w];
            if (w < wv) wp += t;
        }
        int excl = wp + sc0 - v0;
        off2[tid] = excl;
        int dn = b * 256 + tid;
        if (dn < N_NODES) row_start[dn] = base + excl;
    }
    __syncthreads();

    // phase B2: physical reorder into sorted-by-dst LDS array
    for (int k = tid; k < count; k += 1024) {
        unsigned v = el[k];
        int dl = (int)(v >> 20);
        el2[off2[dl] + rk[k]] = v;
    }
    __syncthreads();

    // phase C: attention exp + fully coalesced write of final sorted array
    for (int k = tid; k < count; k += 1024) {
        unsigned v = el2[k];
        unsigned src = v & 0xFFFFFu;
        int dl = (int)(v >> 20);
        float e = s[src] + dloc[dl];
        e = (e > 0.f) ? e : 0.2f * e;          // leaky_relu(0.2)
        float ex = __expf(e);                  // shift-invariant: no global max
        sorted[base + k] = make_uint2(src, __float_as_uint(ex));
    }
    if (b == NB - 1 && tid == 0) row_start[N_NODES] = base + count;
}

// ---------------- K3: aggregation only (bf16 gather, 8-lane edge groups) -----
__global__ __launch_bounds__(256) void k3_agg(const uint2* __restrict__ sorted,
                                              const int* __restrict__ row_start,
                                              const uint4* __restrict__ h4,
                                              uint4* __restrict__ zp) {
    const int lane = threadIdx.x & 63;
    const int node = blockIdx.x * 4 + (threadIdx.x >> 6);  // grid 25000 exact
    const int l8 = lane & 7;
    const int grp = lane >> 3;
    const int beg = row_start[node];
    const int end = row_start[node + 1];
    float a0 = 0.f, a1 = 0.f, a2 = 0.f, a3 = 0.f;
    float a4 = 0.f, a5 = 0.f, a6 = 0.f, a7 = 0.f, se = 0.f;
    int j = beg + grp;
    for (; j + 8 < end; j += 16) {
        uint2 r0 = sorted[j];
        uint2 r1 = sorted[j + 8];
        uint4 g0 = h4[r0.x * 8u + l8];
        uint4 g1 = h4[r1.x * 8u + l8];
        float e0 = __uint_as_float(r0.y), e1 = __uint_as_float(r1.y);
        se += e0 + e1;
        a0 += e0 * blo(g0.x) + e1 * blo(g1.x);
        a1 += e0 * bhi(g0.x) + e1 * bhi(g1.x);
        a2 += e0 * blo(g0.y) + e1 * blo(g1.y);
        a3 += e0 * bhi(g0.y) + e1 * bhi(g1.y);
        a4 += e0 * blo(g0.z) + e1 * blo(g1.z);
        a5 += e0 * bhi(g0.z) + e1 * bhi(g1.z);
        a6 += e0 * blo(g0.w) + e1 * blo(g1.w);
        a7 += e0 * bhi(g0.w) + e1 * bhi(g1.w);
    }
    if (j < end) {   // at most one tail edge per group
        uint2 r = sorted[j];
        uint4 g = h4[r.x * 8u + l8];
        float e = __uint_as_float(r.y);
        se += e;
        a0 += e * blo(g.x); a1 += e * bhi(g.x);
        a2 += e * blo(g.y); a3 += e * bhi(g.y);
        a4 += e * blo(g.z); a5 += e * bhi(g.z);
        a6 += e * blo(g.w); a7 += e * bhi(g.w);
    }
#pragma unroll
    for (int off = 8; off <= 32; off <<= 1) {
        a0 += __shfl_xor(a0, off, 64); a1 += __shfl_xor(a1, off, 64);
        a2 += __shfl_xor(a2, off, 64); a3 += __shfl_xor(a3, off, 64);
        a4 += __shfl_xor(a4, off, 64); a5 += __shfl_xor(a5, off, 64);
        a6 += __shfl_xor(a6, off, 64); a7 += __shfl_xor(a7, off, 64);
        se += __shfl_xor(se, off, 64);
    }
    if (grp == 0) {
        float inv = 1.f / (se + 1e-9f);
        uint4 o;
        o.x = bf16r(fmaxf(a0 * inv, 0.f)) | (bf16r(fmaxf(a1 * inv, 0.f)) << 16);
        o.y = bf16r(fmaxf(a2 * inv, 0.f)) | (bf16r(fmaxf(a3 * inv, 0.f)) << 16);
        o.z = bf16r(fmaxf(a4 * inv, 0.f)) | (bf16r(fmaxf(a5 * inv, 0.f)) << 16);
        o.w = bf16r(fmaxf(a6 * inv, 0.f)) | (bf16r(fmaxf(a7 * inv, 0.f)) << 16);
        zp[node * 8 + l8] = o;   // relu'd, normalized, bf16x8
    }
}

// ---------------- K4: out = z @ W_out^T + b_out (reg-tiled GEMM) -------------
#define K4_M 128
#define ZPAD 133
#define WPAD4 68

__global__ __launch_bounds__(256) void k4_out(const uint2* __restrict__ zp2,
                                              const float* __restrict__ W_out,
                                              const float* __restrict__ b_out,
                                              float* __restrict__ out) {
    __shared__ float zsT[HID * ZPAD];     // [k][m]
    __shared__ float wsT[HID * WPAD4];    // [k][c]
    const int tid = threadIdx.x;
    const int m0g = blockIdx.x * K4_M;    // grid 782, last block partial
    for (int i = tid; i < OUT_DIM * HID; i += 256) {
        int c = i >> 6, k = i & 63;
        wsT[k * WPAD4 + c] = W_out[i];
    }
    for (int i = tid; i < K4_M * 16; i += 256) {   // unpack bf16 z -> fp32 zsT
        int m = i >> 4, q = i & 15;
        int row = m0g + m;
        uint2 v = (row < N_NODES) ? zp2[row * 16 + q] : make_uint2(0u, 0u);
        int kb = q * 4;
        zsT[(kb + 0) * ZPAD + m] = blo(v.x);
        zsT[(kb + 1) * ZPAD + m] = bhi(v.x);
        zsT[(kb + 2) * ZPAD + m] = blo(v.y);
        zsT[(kb + 3) * ZPAD + m] = bhi(v.y);
    }
    __syncthreads();
    const int m0 = (tid & 31) * 4;
    const int c0 = (tid >> 5) * 8;
    float acc[4][8] = {};
#pragma unroll 4
    for (int k = 0; k < HID; ++k) {
        const float4 zv = *(const float4*)&zsT[k * ZPAD + m0];
        const float4 wa = *(const float4*)&wsT[k * WPAD4 + c0];
        const float4 wb = *(const float4*)&wsT[k * WPAD4 + c0 + 4];
#pragma unroll
        for (int i2 = 0; i2 < 4; ++i2) {
            float zi = (&zv.x)[i2];
            acc[i2][0] += zi * wa.x; acc[i2][1] += zi * wa.y;
            acc[i2][2] += zi * wa.z; acc[i2][3] += zi * wa.w;
            acc[i2][4] += zi * wb.x; acc[i2][5] += zi * wb.y;
            acc[i2][6] += zi * wb.z; acc[i2][7] += zi * wb.w;
        }
    }
    const float4 b0 = *(const float4*)&b_out[c0];
    const float4 b1 = *(const float4*)&b_out[c0 + 4];
#pragma unroll
    for (int i2 = 0; i2 < 4; ++i2) {
        int row = m0g + m0 + i2;
        if (row < N_NODES) {
            *(float4*)&out[row * OUT_DIM + c0] =
                make_float4(acc[i2][0] + b0.x, acc[i2][1] + b0.y,
                            acc[i2][2] + b0.z, acc[i2][3] + b0.w);
            *(float4*)&out[row * OUT_DIM + c0 + 4] =
                make_float4(acc[i2][4] + b1.x, acc[i2][5] + b1.y,
                            acc[i2][6] + b1.z, acc[i2][7] + b1.w);
        }
    }
}

extern "C" void kernel_launch(void* const* d_in, const int* in_sizes, int n_in,
                              void* d_out, int out_size, void* d_ws, size_t ws_size,
                              hipStream_t stream) {
    const float* x     = (const float*)d_in[0];
    const int*   ei    = (const int*)d_in[1];
    const float* W_lin = (const float*)d_in[2];
    const float* att   = (const float*)d_in[3];
    const float* W_out = (const float*)d_in[4];
    const float* b_out = (const float*)d_in[5];
    float* out = (float*)d_out;

    // workspace layout (~40.4 MB). ibuf aliases zp (disjoint lifetimes:
    // ibuf dies after k_bucket2; zp is written by k3).
    char* ws = (char*)d_ws;
    unsigned* h2        = (unsigned*)(ws);                    // 12,800,000 B (bf16 h)
    float*    s         = (float*)(ws + 12800000);            //    400,000 B
    float*    d         = (float*)(ws + 13200000);            //    400,000 B
    int*      gcount    = (int*)  (ws + 13600000);            //      1,564 B
    int*      row_start = (int*)  (ws + 14000000);            //    400,016 B
    uint2*    sorted    = (uint2*)(ws + 14800016);            // 12,800,000 B
    unsigned* zp        = (unsigned*)(ws + 27600016);         // 12,800,000 B (bf16 z)
    unsigned* ibuf      = zp;                                 //  7,206,912 B (alias)

    hipMemsetAsync(gcount, 0, NB * sizeof(int), stream);

    p1_bucket<<<P1_BLOCKS, 512, 0, stream>>>(ei, gcount, ibuf);
    k1_lin<<<K1_BLOCKS, 256, 0, stream>>>(x, W_lin, att, (uint4*)h2, s, d);
    k_bucket2<<<NB, 1024, 0, stream>>>(ibuf, gcount, s, d, row_start, sorted);
    k3_agg<<<N_NODES / 4, 256, 0, stream>>>(sorted, row_start, (const uint4*)h2, (uint4*)zp);
    k4_out<<<(N_NODES + K4_M - 1) / K4_M, 256, 0, stream>>>(
        (const uint2*)zp, W_out, b_out, out);
}

// Round 3
// 211.671 us; speedup vs baseline: 1.1311x; 1.1311x over previous
//
#include <hip/hip_runtime.h>

#define N_NODES 100000
#define N_EDGES 1600000
#define IN_DIM 128
#define HID 64
#define OUT_DIM 64

typedef __attribute__((ext_vector_type(8))) short short8;
typedef __attribute__((ext_vector_type(4))) float f32x4;
union FragU { short8 v; unsigned u[4]; };

__device__ __forceinline__ unsigned bf16r(float f) {   // fp32 -> bf16 bits, RNE
    unsigned u = __float_as_uint(f);
    return (u + 0x7FFFu + ((u >> 16) & 1u)) >> 16;
}
__device__ __forceinline__ float blo(unsigned u) { return __uint_as_float(u << 16); }
__device__ __forceinline__ float bhi(unsigned u) { return __uint_as_float(u & 0xFFFF0000u); }

#define K1_BLOCKS 1563          // ceil(6250 tiles / 4 waves)
#define NB 391                  // coarse buckets: dst >> 8
#define CAP 4608                // per-bucket capacity (mean ~4092, +8 sigma)
#define P1_BLOCKS 391           // 4096 edges per pass-1 block
#define P1_EPB 4096

// ---------------- Fused K1 (MFMA linear) + P1 (coarse bucket scatter) --------
// R1-proven fusion: K1's memory waits overlap P1's atomic/scatter waits.
// Per-edge ranks via LDS atomics; ~153K global returning atomics.
__global__ __launch_bounds__(256) void k1_p1(const float* __restrict__ x,
                                             const float* __restrict__ W,
                                             const float* __restrict__ att,
                                             uint4* __restrict__ h4,
                                             float* __restrict__ s,
                                             float* __restrict__ d,
                                             const int* __restrict__ ei,
                                             int* __restrict__ gcount,
                                             unsigned* __restrict__ ibuf) {
    __shared__ float wsL[IN_DIM], wdL[IN_DIM];
    __shared__ float scratch[4 * 64 * 17];   // K1: per-wave [col][row]; P1: cnt/base
    const int tid = threadIdx.x;

    if (blockIdx.x >= K1_BLOCKS) {
        // ---- P1: bucket 4096 edges by dst>>8 ----
        int* cnt  = (int*)scratch;           // [NB]
        int* base = cnt + NB;                // [NB]
        const int blk = blockIdx.x - K1_BLOCKS;
        const int e4base = blk * (P1_EPB / 4);
        for (int i = tid; i < NB; i += 256) cnt[i] = 0;
        __syncthreads();
        int pk[4][4];                        // dst | local_rank<<17
#pragma unroll
        for (int c = 0; c < 4; ++c) {
            int i4 = e4base + c * 256 + tid;
            if (i4 < N_EDGES / 4) {
                int4 dv = ((const int4*)(ei + N_EDGES))[i4];
                pk[c][0] = dv.x | (atomicAdd(&cnt[dv.x >> 8], 1) << 17);
                pk[c][1] = dv.y | (atomicAdd(&cnt[dv.y >> 8], 1) << 17);
                pk[c][2] = dv.z | (atomicAdd(&cnt[dv.z >> 8], 1) << 17);
                pk[c][3] = dv.w | (atomicAdd(&cnt[dv.w >> 8], 1) << 17);
            }
        }
        __syncthreads();
        for (int b = tid; b < NB; b += 256) {        // one returning atomic per bucket
            int c = cnt[b];
            base[b] = c ? atomicAdd(&gcount[b], c) : 0;
        }
        __syncthreads();
#pragma unroll
        for (int c = 0; c < 4; ++c) {
            int i4 = e4base + c * 256 + tid;
            if (i4 < N_EDGES / 4) {
                int4 sv = ((const int4*)ei)[i4];
                int srcs[4] = {sv.x, sv.y, sv.z, sv.w};
#pragma unroll
                for (int j = 0; j < 4; ++j) {
                    unsigned p   = (unsigned)pk[c][j];
                    unsigned dst = p & 0x1FFFFu;
                    unsigned r   = p >> 17;
                    unsigned bk  = dst >> 8;
                    ibuf[bk * CAP + (unsigned)base[bk] + r] =
                        (unsigned)srcs[j] | ((dst & 255u) << 20);
                }
            }
        }
        return;
    }

    // ---- K1: h(bf16) = x @ W^T via MFMA; s,d exact fp32 from x@(W^T att) ----
    if (tid < IN_DIM) {
        float as = 0.f, ad = 0.f;
        for (int c = 0; c < HID; ++c) {
            float w = W[c * IN_DIM + tid];
            as += w * att[c];
            ad += w * att[HID + c];
        }
        wsL[tid] = as; wdL[tid] = ad;
    }
    __syncthreads();

    const int lane = tid & 63;
    const int wv = tid >> 6;
    const int l16 = lane & 15;
    const int quad = lane >> 4;
    const int tile = blockIdx.x * 4 + wv;

    FragU bfrag[4][4];
#pragma unroll
    for (int t = 0; t < 4; ++t) {
#pragma unroll
        for (int ks = 0; ks < 4; ++ks) {
            const float* wp = &W[(t * 16 + l16) * IN_DIM + ks * 32 + quad * 8];
            float4 wa = *(const float4*)wp;
            float4 wb = *(const float4*)(wp + 4);
            bfrag[t][ks].u[0] = bf16r(wa.x) | (bf16r(wa.y) << 16);
            bfrag[t][ks].u[1] = bf16r(wa.z) | (bf16r(wa.w) << 16);
            bfrag[t][ks].u[2] = bf16r(wb.x) | (bf16r(wb.y) << 16);
            bfrag[t][ks].u[3] = bf16r(wb.z) | (bf16r(wb.w) << 16);
        }
    }

    if (tile < N_NODES / 16) {
        const int rowbase = tile * 16;
        const float* xrow = &x[(size_t)(rowbase + l16) * IN_DIM];
        f32x4 acc[4] = {{0.f,0.f,0.f,0.f},{0.f,0.f,0.f,0.f},
                        {0.f,0.f,0.f,0.f},{0.f,0.f,0.f,0.f}};
        float ps = 0.f, pd = 0.f;
#pragma unroll
        for (int ks = 0; ks < 4; ++ks) {
            const int k0 = ks * 32 + quad * 8;
            float4 xa = *(const float4*)&xrow[k0];
            float4 xb = *(const float4*)&xrow[k0 + 4];
            ps += xa.x * wsL[k0]     + xa.y * wsL[k0 + 1]
                + xa.z * wsL[k0 + 2] + xa.w * wsL[k0 + 3]
                + xb.x * wsL[k0 + 4] + xb.y * wsL[k0 + 5]
                + xb.z * wsL[k0 + 6] + xb.w * wsL[k0 + 7];
            pd += xa.x * wdL[k0]     + xa.y * wdL[k0 + 1]
                + xa.z * wdL[k0 + 2] + xa.w * wdL[k0 + 3]
                + xb.x * wdL[k0 + 4] + xb.y * wdL[k0 + 5]
                + xb.z * wdL[k0 + 6] + xb.w * wdL[k0 + 7];
            FragU af;
            af.u[0] = bf16r(xa.x) | (bf16r(xa.y) << 16);
            af.u[1] = bf16r(xa.z) | (bf16r(xa.w) << 16);
            af.u[2] = bf16r(xb.x) | (bf16r(xb.y) << 16);
            af.u[3] = bf16r(xb.z) | (bf16r(xb.w) << 16);
#pragma unroll
            for (int t = 0; t < 4; ++t)
                acc[t] = __builtin_amdgcn_mfma_f32_16x16x32_bf16(
                    af.v, bfrag[t][ks].v, acc[t], 0, 0, 0);
        }
        ps += __shfl_xor(ps, 16, 64); ps += __shfl_xor(ps, 32, 64);
        pd += __shfl_xor(pd, 16, 64); pd += __shfl_xor(pd, 32, 64);
        if (quad == 0) { s[rowbase + l16] = ps; d[rowbase + l16] = pd; }
        float* sc = &scratch[wv * 64 * 17];
#pragma unroll
        for (int t = 0; t < 4; ++t)
#pragma unroll
            for (int r = 0; r < 4; ++r)
                sc[(l16 + 16 * t) * 17 + quad * 4 + r] = acc[t][r];
        // same-wave RAW through LDS: compiler inserts lgkmcnt wait
#pragma unroll
        for (int i = 0; i < 2; ++i) {
            int idx = i * 64 + lane;
            int nrow = idx >> 3, q = idx & 7;
            float v0 = sc[(q * 8 + 0) * 17 + nrow];
            float v1 = sc[(q * 8 + 1) * 17 + nrow];
            float v2 = sc[(q * 8 + 2) * 17 + nrow];
            float v3 = sc[(q * 8 + 3) * 17 + nrow];
            float v4 = sc[(q * 8 + 4) * 17 + nrow];
            float v5 = sc[(q * 8 + 5) * 17 + nrow];
            float v6 = sc[(q * 8 + 6) * 17 + nrow];
            float v7 = sc[(q * 8 + 7) * 17 + nrow];
            uint4 o;
            o.x = bf16r(v0) | (bf16r(v1) << 16);
            o.y = bf16r(v2) | (bf16r(v3) << 16);
            o.z = bf16r(v4) | (bf16r(v5) << 16);
            o.w = bf16r(v6) | (bf16r(v7) << 16);
            h4[(size_t)(rowbase + nrow) * 8 + q] = o;
        }
    }
}

// ---------------- Pass 2: per-bucket LDS counting sort + edge attention ------
// One block per coarse bucket (~4096 edges, 256 dsts). 1024 threads; shfl scan
// (2 barriers); physical LDS reorder so the final sorted write is coalesced.
__global__ __launch_bounds__(1024) void k_bucket2(const unsigned* __restrict__ ibuf,
                                                  const int* __restrict__ gcount,
                                                  const float* __restrict__ s,
                                                  const float* __restrict__ d,
                                                  int* __restrict__ row_start,
                                                  uint2* __restrict__ sorted) {
    __shared__ unsigned el[CAP];
    __shared__ unsigned el2[CAP];
    __shared__ unsigned short rk[CAP];
    __shared__ int cnt2[256], off2[256];
    __shared__ float dloc[256];
    __shared__ int wred[16];
    __shared__ int base_s, cnt_s;
    const int tid  = threadIdx.x;
    const int lane = tid & 63;
    const int wv   = tid >> 6;
    const int b    = blockIdx.x;

    // global base of this bucket = sum of gcount[0..b)
    int part = 0;
    for (int j = tid; j < b; j += 1024) part += gcount[j];
#pragma unroll
    for (int off = 32; off > 0; off >>= 1) part += __shfl_xor(part, off, 64);
    if (lane == 0) wred[wv] = part;
    if (tid < 256) {
        cnt2[tid] = 0;
        int dn = b * 256 + tid;
        dloc[tid] = (dn < N_NODES) ? d[dn] : 0.f;
    }
    __syncthreads();
    if (tid == 0) {
        int t = 0;
#pragma unroll
        for (int w = 0; w < 16; ++w) t += wred[w];
        base_s = t;
        cnt_s = gcount[b];
    }
    __syncthreads();
    const int base  = base_s;
    const int count = cnt_s;

    // phase A: stage edges in LDS, per-dst ranks via LDS atomics
    for (int k = tid; k < count; k += 1024) {
        unsigned v = ibuf[b * CAP + k];
        int dl = (int)(v >> 20);
        int r = atomicAdd(&cnt2[dl], 1);
        el[k] = v;
        rk[k] = (unsigned short)r;
    }
    __syncthreads();

    // phase B: exclusive scan of 256 counters via shfl (2 barriers)
    int v0 = 0, sc0 = 0;
    if (tid < 256) {
        v0 = cnt2[tid];
        sc0 = v0;
#pragma unroll
        for (int off = 1; off < 64; off <<= 1) {
            int t = __shfl_up(sc0, off, 64);
            if (lane >= off) sc0 += t;
        }
        if (lane == 63) wred[wv] = sc0;     // wv in 0..3 here
    }
    __syncthreads();
    if (tid < 256) {
        int wp = 0;
#pragma unroll
        for (int w = 0; w < 4; ++w) {
            int t = wred[w];
            if (w < wv) wp += t;
        }
        int excl = wp + sc0 - v0;
        off2[tid] = excl;
        int dn = b * 256 + tid;
        if (dn < N_NODES) row_start[dn] = base + excl;
    }
    __syncthreads();

    // phase B2: physical reorder into sorted-by-dst LDS array
    for (int k = tid; k < count; k += 1024) {
        unsigned v = el[k];
        int dl = (int)(v >> 20);
        el2[off2[dl] + rk[k]] = v;
    }
    __syncthreads();

    // phase C: attention exp + fully coalesced write of final sorted array
    for (int k = tid; k < count; k += 1024) {
        unsigned v = el2[k];
        unsigned src = v & 0xFFFFFu;
        int dl = (int)(v >> 20);
        float e = s[src] + dloc[dl];
        e = (e > 0.f) ? e : 0.2f * e;          // leaky_relu(0.2)
        float ex = __expf(e);                  // shift-invariant: no global max
        sorted[base + k] = make_uint2(src, __float_as_uint(ex));
    }
    if (b == NB - 1 && tid == 0) row_start[N_NODES] = base + count;
}

// ---------------- K3: aggregation, one 8-lane group per node -----------------
// 8 nodes per wave; each lane owns 8 output columns -> NO cross-lane reduction.
// 4-edge unroll for memory-level parallelism. No LDS; ~45 VGPR -> full occupancy.
__global__ __launch_bounds__(256) void k3_agg(const uint2* __restrict__ sorted,
                                              const int* __restrict__ row_start,
                                              const uint4* __restrict__ h4,
                                              uint4* __restrict__ zp) {
    const int l8 = threadIdx.x & 7;
    const int node = blockIdx.x * 32 + (threadIdx.x >> 3);   // grid 3125 exact
    const int beg = row_start[node];
    const int end = row_start[node + 1];
    float a0 = 0.f, a1 = 0.f, a2 = 0.f, a3 = 0.f;
    float a4 = 0.f, a5 = 0.f, a6 = 0.f, a7 = 0.f, se = 0.f;
    int j = beg;
    for (; j + 3 < end; j += 4) {
        uint2 r0 = sorted[j];        // group-uniform: L1 broadcast
        uint2 r1 = sorted[j + 1];
        uint2 r2 = sorted[j + 2];
        uint2 r3 = sorted[j + 3];
        uint4 g0 = h4[r0.x * 8u + l8];
        uint4 g1 = h4[r1.x * 8u + l8];
        uint4 g2 = h4[r2.x * 8u + l8];
        uint4 g3 = h4[r3.x * 8u + l8];
        float e0 = __uint_as_float(r0.y), e1 = __uint_as_float(r1.y);
        float e2 = __uint_as_float(r2.y), e3 = __uint_as_float(r3.y);
        se += (e0 + e1) + (e2 + e3);
        a0 += e0 * blo(g0.x) + e1 * blo(g1.x) + e2 * blo(g2.x) + e3 * blo(g3.x);
        a1 += e0 * bhi(g0.x) + e1 * bhi(g1.x) + e2 * bhi(g2.x) + e3 * bhi(g3.x);
        a2 += e0 * blo(g0.y) + e1 * blo(g1.y) + e2 * blo(g2.y) + e3 * blo(g3.y);
        a3 += e0 * bhi(g0.y) + e1 * bhi(g1.y) + e2 * bhi(g2.y) + e3 * bhi(g3.y);
        a4 += e0 * blo(g0.z) + e1 * blo(g1.z) + e2 * blo(g2.z) + e3 * blo(g3.z);
        a5 += e0 * bhi(g0.z) + e1 * bhi(g1.z) + e2 * bhi(g2.z) + e3 * bhi(g3.z);
        a6 += e0 * blo(g0.w) + e1 * blo(g1.w) + e2 * blo(g2.w) + e3 * blo(g3.w);
        a7 += e0 * bhi(g0.w) + e1 * bhi(g1.w) + e2 * bhi(g2.w) + e3 * bhi(g3.w);
    }
    for (; j < end; ++j) {
        uint2 r = sorted[j];
        uint4 g = h4[r.x * 8u + l8];
        float e = __uint_as_float(r.y);
        se += e;
        a0 += e * blo(g.x); a1 += e * bhi(g.x);
        a2 += e * blo(g.y); a3 += e * bhi(g.y);
        a4 += e * blo(g.z); a5 += e * bhi(g.z);
        a6 += e * blo(g.w); a7 += e * bhi(g.w);
    }
    float inv = 1.f / (se + 1e-9f);
    uint4 o;
    o.x = bf16r(fmaxf(a0 * inv, 0.f)) | (bf16r(fmaxf(a1 * inv, 0.f)) << 16);
    o.y = bf16r(fmaxf(a2 * inv, 0.f)) | (bf16r(fmaxf(a3 * inv, 0.f)) << 16);
    o.z = bf16r(fmaxf(a4 * inv, 0.f)) | (bf16r(fmaxf(a5 * inv, 0.f)) << 16);
    o.w = bf16r(fmaxf(a6 * inv, 0.f)) | (bf16r(fmaxf(a7 * inv, 0.f)) << 16);
    zp[node * 8 + l8] = o;   // relu'd, normalized, bf16x8; coalesced per wave
}

// ---------------- K4: out = z @ W_out^T + b_out (reg-tiled GEMM) -------------
#define K4_M 128
#define ZPAD 133
#define WPAD4 68

__global__ __launch_bounds__(256) void k4_out(const uint2* __restrict__ zp2,
                                              const float* __restrict__ W_out,
                                              const float* __restrict__ b_out,
                                              float* __restrict__ out) {
    __shared__ float zsT[HID * ZPAD];     // [k][m]
    __shared__ float wsT[HID * WPAD4];    // [k][c]
    const int tid = threadIdx.x;
    const int m0g = blockIdx.x * K4_M;    // grid 782, last block partial
    for (int i = tid; i < OUT_DIM * HID; i += 256) {
        int c = i >> 6, k = i & 63;
        wsT[k * WPAD4 + c] = W_out[i];
    }
    for (int i = tid; i < K4_M * 16; i += 256) {   // unpack bf16 z -> fp32 zsT
        int m = i >> 4, q = i & 15;
        int row = m0g + m;
        uint2 v = (row < N_NODES) ? zp2[row * 16 + q] : make_uint2(0u, 0u);
        int kb = q * 4;
        zsT[(kb + 0) * ZPAD + m] = blo(v.x);
        zsT[(kb + 1) * ZPAD + m] = bhi(v.x);
        zsT[(kb + 2) * ZPAD + m] = blo(v.y);
        zsT[(kb + 3) * ZPAD + m] = bhi(v.y);
    }
    __syncthreads();
    const int m0 = (tid & 31) * 4;
    const int c0 = (tid >> 5) * 8;
    float acc[4][8] = {};
#pragma unroll 4
    for (int k = 0; k < HID; ++k) {
        const float4 zv = *(const float4*)&zsT[k * ZPAD + m0];
        const float4 wa = *(const float4*)&wsT[k * WPAD4 + c0];
        const float4 wb = *(const float4*)&wsT[k * WPAD4 + c0 + 4];
#pragma unroll
        for (int i2 = 0; i2 < 4; ++i2) {
            float zi = (&zv.x)[i2];
            acc[i2][0] += zi * wa.x; acc[i2][1] += zi * wa.y;
            acc[i2][2] += zi * wa.z; acc[i2][3] += zi * wa.w;
            acc[i2][4] += zi * wb.x; acc[i2][5] += zi * wb.y;
            acc[i2][6] += zi * wb.z; acc[i2][7] += zi * wb.w;
        }
    }
    const float4 b0 = *(const float4*)&b_out[c0];
    const float4 b1 = *(const float4*)&b_out[c0 + 4];
#pragma unroll
    for (int i2 = 0; i2 < 4; ++i2) {
        int row = m0g + m0 + i2;
        if (row < N_NODES) {
            *(float4*)&out[row * OUT_DIM + c0] =
                make_float4(acc[i2][0] + b0.x, acc[i2][1] + b0.y,
                            acc[i2][2] + b0.z, acc[i2][3] + b0.w);
            *(float4*)&out[row * OUT_DIM + c0 + 4] =
                make_float4(acc[i2][4] + b1.x, acc[i2][5] + b1.y,
                            acc[i2][6] + b1.z, acc[i2][7] + b1.w);
        }
    }
}

extern "C" void kernel_launch(void* const* d_in, const int* in_sizes, int n_in,
                              void* d_out, int out_size, void* d_ws, size_t ws_size,
                              hipStream_t stream) {
    const float* x     = (const float*)d_in[0];
    const int*   ei    = (const int*)d_in[1];
    const float* W_lin = (const float*)d_in[2];
    const float* att   = (const float*)d_in[3];
    const float* W_out = (const float*)d_in[4];
    const float* b_out = (const float*)d_in[5];
    float* out = (float*)d_out;

    // workspace layout (~40.4 MB). ibuf aliases zp (disjoint lifetimes:
    // ibuf dies after k_bucket2; zp is written by k3).
    char* ws = (char*)d_ws;
    unsigned* h2        = (unsigned*)(ws);                    // 12,800,000 B (bf16 h)
    float*    s         = (float*)(ws + 12800000);            //    400,000 B
    float*    d         = (float*)(ws + 13200000);            //    400,000 B
    int*      gcount    = (int*)  (ws + 13600000);            //      1,564 B
    int*      row_start = (int*)  (ws + 14000000);            //    400,016 B
    uint2*    sorted    = (uint2*)(ws + 14800016);            // 12,800,000 B
    unsigned* zp        = (unsigned*)(ws + 27600016);         // 12,800,000 B (bf16 z)
    unsigned* ibuf      = zp;                                 //  7,206,912 B (alias)

    hipMemsetAsync(gcount, 0, NB * sizeof(int), stream);

    k1_p1<<<K1_BLOCKS + P1_BLOCKS, 256, 0, stream>>>(
        x, W_lin, att, (uint4*)h2, s, d, ei, gcount, ibuf);
    k_bucket2<<<NB, 1024, 0, stream>>>(ibuf, gcount, s, d, row_start, sorted);
    k3_agg<<<N_NODES / 32, 256, 0, stream>>>(sorted, row_start, (const uint4*)h2, (uint4*)zp);
    k4_out<<<(N_NODES + K4_M - 1) / K4_M, 256, 0, stream>>>(
        (const uint2*)zp, W_out, b_out, out);
}

// Round 4
// 203.855 us; speedup vs baseline: 1.1745x; 1.0383x over previous
//
#include <hip/hip_runtime.h>

#define N_NODES 100000
#define N_EDGES 1600000
#define IN_DIM 128
#define HID 64
#define OUT_DIM 64

typedef __attribute__((ext_vector_type(8))) short short8;
typedef __attribute__((ext_vector_type(4))) float f32x4;
union FragU { short8 v; unsigned u[4]; };

__device__ __forceinline__ unsigned bf16r(float f) {   // fp32 -> bf16 bits, RNE
    unsigned u = __float_as_uint(f);
    return (u + 0x7FFFu + ((u >> 16) & 1u)) >> 16;
}
__device__ __forceinline__ float blo(unsigned u) { return __uint_as_float(u << 16); }
__device__ __forceinline__ float bhi(unsigned u) { return __uint_as_float(u & 0xFFFF0000u); }

#define K1_BLOCKS 1563          // ceil(6250 tiles / 4 waves)
#define NB 391                  // coarse buckets: dst >> 8
#define CAP 4608                // per-bucket capacity (mean ~4092, +8 sigma)
#define P1_BLOCKS 391           // 4096 edges per pass-1 block
#define P1_EPB 4096

// ---------------- Fused K1 (MFMA linear) + P1 (coarse bucket scatter) --------
// R1-proven fusion: K1's memory waits overlap P1's atomic/scatter waits.
// Per-edge ranks via LDS atomics; ~153K global returning atomics.
__global__ __launch_bounds__(256) void k1_p1(const float* __restrict__ x,
                                             const float* __restrict__ W,
                                             const float* __restrict__ att,
                                             uint4* __restrict__ h4,
                                             float* __restrict__ s,
                                             float* __restrict__ d,
                                             const int* __restrict__ ei,
                                             int* __restrict__ gcount,
                                             unsigned* __restrict__ ibuf) {
    __shared__ float wsL[IN_DIM], wdL[IN_DIM];
    __shared__ float scratch[4 * 64 * 17];   // K1: per-wave [col][row]; P1: cnt/base
    const int tid = threadIdx.x;

    if (blockIdx.x >= K1_BLOCKS) {
        // ---- P1: bucket 4096 edges by dst>>8 ----
        int* cnt  = (int*)scratch;           // [NB]
        int* base = cnt + NB;                // [NB]
        const int blk = blockIdx.x - K1_BLOCKS;
        const int e4base = blk * (P1_EPB / 4);
        for (int i = tid; i < NB; i += 256) cnt[i] = 0;
        __syncthreads();
        int pk[4][4];                        // dst | local_rank<<17
#pragma unroll
        for (int c = 0; c < 4; ++c) {
            int i4 = e4base + c * 256 + tid;
            if (i4 < N_EDGES / 4) {
                int4 dv = ((const int4*)(ei + N_EDGES))[i4];
                pk[c][0] = dv.x | (atomicAdd(&cnt[dv.x >> 8], 1) << 17);
                pk[c][1] = dv.y | (atomicAdd(&cnt[dv.y >> 8], 1) << 17);
                pk[c][2] = dv.z | (atomicAdd(&cnt[dv.z >> 8], 1) << 17);
                pk[c][3] = dv.w | (atomicAdd(&cnt[dv.w >> 8], 1) << 17);
            }
        }
        __syncthreads();
        for (int b = tid; b < NB; b += 256) {        // one returning atomic per bucket
            int c = cnt[b];
            base[b] = c ? atomicAdd(&gcount[b], c) : 0;
        }
        __syncthreads();
#pragma unroll
        for (int c = 0; c < 4; ++c) {
            int i4 = e4base + c * 256 + tid;
            if (i4 < N_EDGES / 4) {
                int4 sv = ((const int4*)ei)[i4];
                int srcs[4] = {sv.x, sv.y, sv.z, sv.w};
#pragma unroll
                for (int j = 0; j < 4; ++j) {
                    unsigned p   = (unsigned)pk[c][j];
                    unsigned dst = p & 0x1FFFFu;
                    unsigned r   = p >> 17;
                    unsigned bk  = dst >> 8;
                    ibuf[bk * CAP + (unsigned)base[bk] + r] =
                        (unsigned)srcs[j] | ((dst & 255u) << 20);
                }
            }
        }
        return;
    }

    // ---- K1: h(bf16) = x @ W^T via MFMA; s,d exact fp32 from x@(W^T att) ----
    if (tid < IN_DIM) {
        float as = 0.f, ad = 0.f;
#pragma unroll
        for (int c = 0; c < HID; ++c) {
            float w = W[c * IN_DIM + tid];
            as += w * att[c];
            ad += w * att[HID + c];
        }
        wsL[tid] = as; wdL[tid] = ad;
    }
    __syncthreads();

    const int lane = tid & 63;
    const int wv = tid >> 6;
    const int l16 = lane & 15;
    const int quad = lane >> 4;
    const int tile = blockIdx.x * 4 + wv;

    FragU bfrag[4][4];
#pragma unroll
    for (int t = 0; t < 4; ++t) {
#pragma unroll
        for (int ks = 0; ks < 4; ++ks) {
            const float* wp = &W[(t * 16 + l16) * IN_DIM + ks * 32 + quad * 8];
            float4 wa = *(const float4*)wp;
            float4 wb = *(const float4*)(wp + 4);
            bfrag[t][ks].u[0] = bf16r(wa.x) | (bf16r(wa.y) << 16);
            bfrag[t][ks].u[1] = bf16r(wa.z) | (bf16r(wa.w) << 16);
            bfrag[t][ks].u[2] = bf16r(wb.x) | (bf16r(wb.y) << 16);
            bfrag[t][ks].u[3] = bf16r(wb.z) | (bf16r(wb.w) << 16);
        }
    }

    if (tile < N_NODES / 16) {
        const int rowbase = tile * 16;
        const float* xrow = &x[(size_t)(rowbase + l16) * IN_DIM];
        f32x4 acc[4] = {{0.f,0.f,0.f,0.f},{0.f,0.f,0.f,0.f},
                        {0.f,0.f,0.f,0.f},{0.f,0.f,0.f,0.f}};
        float ps = 0.f, pd = 0.f;
#pragma unroll
        for (int ks = 0; ks < 4; ++ks) {
            const int k0 = ks * 32 + quad * 8;
            float4 xa = *(const float4*)&xrow[k0];
            float4 xb = *(const float4*)&xrow[k0 + 4];
            ps += xa.x * wsL[k0]     + xa.y * wsL[k0 + 1]
                + xa.z * wsL[k0 + 2] + xa.w * wsL[k0 + 3]
                + xb.x * wsL[k0 + 4] + xb.y * wsL[k0 + 5]
                + xb.z * wsL[k0 + 6] + xb.w * wsL[k0 + 7];
            pd += xa.x * wdL[k0]     + xa.y * wdL[k0 + 1]
                + xa.z * wdL[k0 + 2] + xa.w * wdL[k0 + 3]
                + xb.x * wdL[k0 + 4] + xb.y * wdL[k0 + 5]
                + xb.z * wdL[k0 + 6] + xb.w * wdL[k0 + 7];
            FragU af;
            af.u[0] = bf16r(xa.x) | (bf16r(xa.y) << 16);
            af.u[1] = bf16r(xa.z) | (bf16r(xa.w) << 16);
            af.u[2] = bf16r(xb.x) | (bf16r(xb.y) << 16);
            af.u[3] = bf16r(xb.z) | (bf16r(xb.w) << 16);
#pragma unroll
            for (int t = 0; t < 4; ++t)
                acc[t] = __builtin_amdgcn_mfma_f32_16x16x32_bf16(
                    af.v, bfrag[t][ks].v, acc[t], 0, 0, 0);
        }
        ps += __shfl_xor(ps, 16, 64); ps += __shfl_xor(ps, 32, 64);
        pd += __shfl_xor(pd, 16, 64); pd += __shfl_xor(pd, 32, 64);
        if (quad == 0) { s[rowbase + l16] = ps; d[rowbase + l16] = pd; }
        float* sc = &scratch[wv * 64 * 17];
#pragma unroll
        for (int t = 0; t < 4; ++t)
#pragma unroll
            for (int r = 0; r < 4; ++r)
                sc[(l16 + 16 * t) * 17 + quad * 4 + r] = acc[t][r];
        // same-wave RAW through LDS: compiler inserts lgkmcnt wait
#pragma unroll
        for (int i = 0; i < 2; ++i) {
            int idx = i * 64 + lane;
            int nrow = idx >> 3, q = idx & 7;
            float v0 = sc[(q * 8 + 0) * 17 + nrow];
            float v1 = sc[(q * 8 + 1) * 17 + nrow];
            float v2 = sc[(q * 8 + 2) * 17 + nrow];
            float v3 = sc[(q * 8 + 3) * 17 + nrow];
            float v4 = sc[(q * 8 + 4) * 17 + nrow];
            float v5 = sc[(q * 8 + 5) * 17 + nrow];
            float v6 = sc[(q * 8 + 6) * 17 + nrow];
            float v7 = sc[(q * 8 + 7) * 17 + nrow];
            uint4 o;
            o.x = bf16r(v0) | (bf16r(v1) << 16);
            o.y = bf16r(v2) | (bf16r(v3) << 16);
            o.z = bf16r(v4) | (bf16r(v5) << 16);
            o.w = bf16r(v6) | (bf16r(v7) << 16);
            h4[(size_t)(rowbase + nrow) * 8 + q] = o;
        }
    }
}

// ---------------- Fused sort + attention + aggregation -----------------------
// One block per coarse bucket (~4096 edges, 256 dsts). Rank-sort in LDS,
// compute exp(leaky(s+d)) in registers, aggregate h directly from LDS edge
// records. `sorted`/`row_start` never materialize; no global prefix needed.
__global__ __launch_bounds__(1024) void k_sort_agg(const unsigned* __restrict__ ibuf,
                                                   const int* __restrict__ gcount,
                                                   const float* __restrict__ s,
                                                   const float* __restrict__ d,
                                                   const uint4* __restrict__ h4,
                                                   uint4* __restrict__ zp) {
    __shared__ uint2 el[CAP];            // (src, exp-bits), sorted by dst
    __shared__ int cnt2[256], off2[256];
    __shared__ float dloc[256];
    __shared__ int wred[4];
    const int tid  = threadIdx.x;
    const int lane = tid & 63;
    const int wv   = tid >> 6;
    const int b    = blockIdx.x;

    if (tid < 256) {
        cnt2[tid] = 0;
        int dn = b * 256 + tid;
        dloc[tid] = (dn < N_NODES) ? d[dn] : 0.f;
    }
    __syncthreads();
    const int count = gcount[b];

    // pass A: read bucket edges, per-dst ranks via LDS atomics, keep in regs
    unsigned vk[5];
    int rk_[5];
#pragma unroll
    for (int ki = 0; ki < 5; ++ki) {
        int k = tid + ki * 1024;
        vk[ki] = 0u; rk_[ki] = -1;
        if (k < count) {
            unsigned v = ibuf[(size_t)b * CAP + k];
            int dl = (int)(v >> 20);
            rk_[ki] = atomicAdd(&cnt2[dl], 1);
            vk[ki] = v;
        }
    }
    __syncthreads();

    // exclusive scan of 256 counters via shfl (2 barriers); cnt2 preserved
    int v0 = 0, sc0 = 0;
    if (tid < 256) {
        v0 = cnt2[tid];
        sc0 = v0;
#pragma unroll
        for (int off = 1; off < 64; off <<= 1) {
            int t = __shfl_up(sc0, off, 64);
            if (lane >= off) sc0 += t;
        }
        if (lane == 63) wred[wv] = sc0;   // wv in 0..3 here
    }
    __syncthreads();
    if (tid < 256) {
        int wp = 0;
#pragma unroll
        for (int w = 0; w < 4; ++w) {
            int t = wred[w];
            if (w < wv) wp += t;
        }
        off2[tid] = wp + sc0 - v0;
    }
    __syncthreads();

    // pass B: attention exp (5-deep MLP on s gathers) + LDS scatter by dst
#pragma unroll
    for (int ki = 0; ki < 5; ++ki) {
        if (rk_[ki] >= 0) {
            unsigned v = vk[ki];
            unsigned src = v & 0xFFFFFu;
            int dl = (int)(v >> 20);
            float e = s[src] + dloc[dl];
            e = (e > 0.f) ? e : 0.2f * e;          // leaky_relu(0.2)
            float ex = __expf(e);                  // shift-invariant
            el[off2[dl] + rk_[ki]] = make_uint2(src, __float_as_uint(ex));
        }
    }
    __syncthreads();

    // aggregation: 128 groups of 8 lanes; each group owns dsts g and g+128.
    // Each lane owns 8 output columns -> no cross-lane reduction.
    const int l8 = tid & 7;
    const int g = tid >> 3;
#pragma unroll
    for (int half = 0; half < 2; ++half) {
        const int dl = g + half * 128;
        const int node = b * 256 + dl;
        if (node < N_NODES) {
            const int o = off2[dl];
            const int n = cnt2[dl];
            float a0 = 0.f, a1 = 0.f, a2 = 0.f, a3 = 0.f;
            float a4 = 0.f, a5 = 0.f, a6 = 0.f, a7 = 0.f, se = 0.f;
            int j = 0;
            for (; j + 3 < n; j += 4) {
                uint2 r0 = el[o + j];          // LDS b64, group-broadcast
                uint2 r1 = el[o + j + 1];
                uint2 r2 = el[o + j + 2];
                uint2 r3 = el[o + j + 3];
                uint4 g0 = h4[(size_t)r0.x * 8u + l8];
                uint4 g1 = h4[(size_t)r1.x * 8u + l8];
                uint4 g2 = h4[(size_t)r2.x * 8u + l8];
                uint4 g3 = h4[(size_t)r3.x * 8u + l8];
                float e0 = __uint_as_float(r0.y), e1 = __uint_as_float(r1.y);
                float e2 = __uint_as_float(r2.y), e3 = __uint_as_float(r3.y);
                se += (e0 + e1) + (e2 + e3);
                a0 += e0 * blo(g0.x) + e1 * blo(g1.x) + e2 * blo(g2.x) + e3 * blo(g3.x);
                a1 += e0 * bhi(g0.x) + e1 * bhi(g1.x) + e2 * bhi(g2.x) + e3 * bhi(g3.x);
                a2 += e0 * blo(g0.y) + e1 * blo(g1.y) + e2 * blo(g2.y) + e3 * blo(g3.y);
                a3 += e0 * bhi(g0.y) + e1 * bhi(g1.y) + e2 * bhi(g2.y) + e3 * bhi(g3.y);
                a4 += e0 * blo(g0.z) + e1 * blo(g1.z) + e2 * blo(g2.z) + e3 * blo(g3.z);
                a5 += e0 * bhi(g0.z) + e1 * bhi(g1.z) + e2 * bhi(g2.z) + e3 * bhi(g3.z);
                a6 += e0 * blo(g0.w) + e1 * blo(g1.w) + e2 * blo(g2.w) + e3 * blo(g3.w);
                a7 += e0 * bhi(g0.w) + e1 * bhi(g1.w) + e2 * bhi(g2.w) + e3 * bhi(g3.w);
            }
            for (; j < n; ++j) {
                uint2 r = el[o + j];
                uint4 gg = h4[(size_t)r.x * 8u + l8];
                float e = __uint_as_float(r.y);
                se += e;
                a0 += e * blo(gg.x); a1 += e * bhi(gg.x);
                a2 += e * blo(gg.y); a3 += e * bhi(gg.y);
                a4 += e * blo(gg.z); a5 += e * bhi(gg.z);
                a6 += e * blo(gg.w); a7 += e * bhi(gg.w);
            }
            float inv = 1.f / (se + 1e-9f);
            uint4 o4;
            o4.x = bf16r(fmaxf(a0 * inv, 0.f)) | (bf16r(fmaxf(a1 * inv, 0.f)) << 16);
            o4.y = bf16r(fmaxf(a2 * inv, 0.f)) | (bf16r(fmaxf(a3 * inv, 0.f)) << 16);
            o4.z = bf16r(fmaxf(a4 * inv, 0.f)) | (bf16r(fmaxf(a5 * inv, 0.f)) << 16);
            o4.w = bf16r(fmaxf(a6 * inv, 0.f)) | (bf16r(fmaxf(a7 * inv, 0.f)) << 16);
            zp[(size_t)node * 8 + l8] = o4;   // relu'd, normalized, bf16x8
        }
    }
}

// ---------------- K4: out = z @ W_out^T + b_out (reg-tiled GEMM) -------------
#define K4_M 128
#define ZPAD 132
#define WPAD4 68

__global__ __launch_bounds__(256) void k4_out(const uint2* __restrict__ zp2,
                                              const float* __restrict__ W_out,
                                              const float* __restrict__ b_out,
                                              float* __restrict__ out) {
    __shared__ float zsT[HID * ZPAD];     // [k][m]
    __shared__ float wsT[HID * WPAD4];    // [k][c]
    const int tid = threadIdx.x;
    const int m0g = blockIdx.x * K4_M;    // grid 782, last block partial
    for (int i = tid; i < OUT_DIM * HID; i += 256) {
        int c = i >> 6, k = i & 63;
        wsT[k * WPAD4 + c] = W_out[i];
    }
    for (int i = tid; i < K4_M * 16; i += 256) {   // unpack bf16 z -> fp32 zsT
        int m = i >> 4, q = i & 15;
        int row = m0g + m;
        uint2 v = (row < N_NODES) ? zp2[row * 16 + q] : make_uint2(0u, 0u);
        int kb = q * 4;
        zsT[(kb + 0) * ZPAD + m] = blo(v.x);
        zsT[(kb + 1) * ZPAD + m] = bhi(v.x);
        zsT[(kb + 2) * ZPAD + m] = blo(v.y);
        zsT[(kb + 3) * ZPAD + m] = bhi(v.y);
    }
    __syncthreads();
    const int m0 = (tid & 31) * 4;
    const int c0 = (tid >> 5) * 8;
    float acc[4][8] = {};
#pragma unroll 4
    for (int k = 0; k < HID; ++k) {
        const float4 zv = *(const float4*)&zsT[k * ZPAD + m0];
        const float4 wa = *(const float4*)&wsT[k * WPAD4 + c0];
        const float4 wb = *(const float4*)&wsT[k * WPAD4 + c0 + 4];
#pragma unroll
        for (int i2 = 0; i2 < 4; ++i2) {
            float zi = (&zv.x)[i2];
            acc[i2][0] += zi * wa.x; acc[i2][1] += zi * wa.y;
            acc[i2][2] += zi * wa.z; acc[i2][3] += zi * wa.w;
            acc[i2][4] += zi * wb.x; acc[i2][5] += zi * wb.y;
            acc[i2][6] += zi * wb.z; acc[i2][7] += zi * wb.w;
        }
    }
    const float4 b0 = *(const float4*)&b_out[c0];
    const float4 b1 = *(const float4*)&b_out[c0 + 4];
#pragma unroll
    for (int i2 = 0; i2 < 4; ++i2) {
        int row = m0g + m0 + i2;
        if (row < N_NODES) {
            *(float4*)&out[row * OUT_DIM + c0] =
                make_float4(acc[i2][0] + b0.x, acc[i2][1] + b0.y,
                            acc[i2][2] + b0.z, acc[i2][3] + b0.w);
            *(float4*)&out[row * OUT_DIM + c0 + 4] =
                make_float4(acc[i2][4] + b1.x, acc[i2][5] + b1.y,
                            acc[i2][6] + b1.z, acc[i2][7] + b1.w);
        }
    }
}

extern "C" void kernel_launch(void* const* d_in, const int* in_sizes, int n_in,
                              void* d_out, int out_size, void* d_ws, size_t ws_size,
                              hipStream_t stream) {
    const float* x     = (const float*)d_in[0];
    const int*   ei    = (const int*)d_in[1];
    const float* W_lin = (const float*)d_in[2];
    const float* att   = (const float*)d_in[3];
    const float* W_out = (const float*)d_in[4];
    const float* b_out = (const float*)d_in[5];
    float* out = (float*)d_out;

    // workspace layout (~40.4 MB). ibuf is its own region now (k_sort_agg
    // reads ibuf AND writes zp concurrently across blocks -> must not alias).
    char* ws = (char*)d_ws;
    unsigned* h2        = (unsigned*)(ws);                    // 12,800,000 B (bf16 h)
    float*    s         = (float*)(ws + 12800000);            //    400,000 B
    float*    d         = (float*)(ws + 13200000);            //    400,000 B
    int*      gcount    = (int*)  (ws + 13600000);            //      1,564 B
    unsigned* ibuf      = (unsigned*)(ws + 14800016);         //  7,206,912 B
    unsigned* zp        = (unsigned*)(ws + 27600016);         // 12,800,000 B (bf16 z)

    hipMemsetAsync(gcount, 0, NB * sizeof(int), stream);

    k1_p1<<<K1_BLOCKS + P1_BLOCKS, 256, 0, stream>>>(
        x, W_lin, att, (uint4*)h2, s, d, ei, gcount, ibuf);
    k_sort_agg<<<NB, 1024, 0, stream>>>(ibuf, gcount, s, d, (const uint4*)h2, (uint4*)zp);
    k4_out<<<(N_NODES + K4_M - 1) / K4_M, 256, 0, stream>>>(
        (const uint2*)zp, W_out, b_out, out);
}